// Round 10
// baseline (1979.752 us; speedup 1.0000x reference)
//
#include <hip/hip_runtime.h>
#include <stdint.h>

// Problem constants
#define N_ROWS 16384   // 16*1024 flattened input rows
#define N_EMB  8192    // codebook size
#define C_DIM  256     // embedding dim
#define NKT    8       // pure-bf16 GEMM: K=256, 8 K-tiles of 32 (R9-validated)

// d_out layout (float element offsets), outputs concatenated in return order:
// loss(1), quantized_st(16*1024*3*256), perplexity(1), encoding_indices(16384*3), distances(16384*8192)
#define OFF_LOSS 0ull
#define OFF_Q    1ull
#define OFF_PERP 12582913ull
#define OFF_IDX  12582914ull
#define OFF_DIST 12632066ull

typedef short bf16x8 __attribute__((ext_vector_type(8)));
typedef float f32x4  __attribute__((ext_vector_type(4)));
typedef float f32x2  __attribute__((ext_vector_type(2)));

#define LT(av,ai,bv,bi) (((av) < (bv)) || ((av) == (bv) && (ai) < (bi)))

// insert (d,ii) into sorted triple (v0<=v1<=v2 by LT)
__device__ __forceinline__ void ins3(float d, int ii,
    float& v0, int& i0, float& v1, int& i1, float& v2, int& i2){
  if (LT(d, ii, v2, i2)){
    if (LT(d, ii, v1, i1)){
      v2 = v1; i2 = i1;
      if (LT(d, ii, v0, i0)){ v1 = v0; i1 = i0; v0 = d; i0 = ii; }
      else                  { v1 = d;  i1 = ii; }
    } else { v2 = d; i2 = ii; }
  }
}

// butterfly-merge step: merge my sorted triple with lane^off's triple (k_mq only)
__device__ __forceinline__ void mrg3(int off,
    float& v0, int& i0, float& v1, int& i1, float& v2, int& i2){
  float b0 = __shfl_xor(v0, off), b1 = __shfl_xor(v1, off), b2 = __shfl_xor(v2, off);
  int   j0 = __shfl_xor(i0, off), j1 = __shfl_xor(i1, off), j2 = __shfl_xor(i2, off);
  float a0 = v0, a1 = v1, a2 = v2; int x0 = i0, x1 = i1, x2 = i2;
  float r0, r1, r2; int s0, s1, s2;
  if (LT(a0, x0, b0, j0)){ r0 = a0; s0 = x0; a0 = a1; x0 = x1; a1 = a2; x1 = x2; a2 = __builtin_inff(); x2 = 0x7fffffff; }
  else                   { r0 = b0; s0 = j0; b0 = b1; j0 = j1; b1 = b2; j1 = j2; b2 = __builtin_inff(); j2 = 0x7fffffff; }
  if (LT(a0, x0, b0, j0)){ r1 = a0; s1 = x0; a0 = a1; x0 = x1; a1 = a2; x1 = x2; a2 = __builtin_inff(); x2 = 0x7fffffff; }
  else                   { r1 = b0; s1 = j0; b0 = b1; j0 = j1; b1 = b2; j1 = j2; b2 = __builtin_inff(); j2 = 0x7fffffff; }
  if (LT(a0, x0, b0, j0)){ r2 = a0; s2 = x0; }
  else                   { r2 = b0; s2 = j0; }
  v0 = r0; i0 = s0; v1 = r1; i1 = s1; v2 = r2; i2 = s2;
}

// ---------------- prep: fp32 -> bf16 (rne), K-chunk-major layout + fp32 row norms ----------------
__device__ __forceinline__ unsigned short f2bf_rne(float f){
  unsigned u = __float_as_uint(f);
  unsigned r = 0x7fffu + ((u >> 16) & 1u);
  return (unsigned short)((u + r) >> 16);
}

__global__ __launch_bounds__(256) void k_prep(
    const float* __restrict__ X, const float* __restrict__ E,
    short* __restrict__ XT, short* __restrict__ ET,
    float* __restrict__ xnorm, float* __restrict__ enorm)
{
  int b = blockIdx.x; int tid = threadIdx.x;
  const float* src; short* dst; float* nrm; int r0, NR;
  if (b < N_ROWS / 8){ r0 = b * 8;                src = X; dst = XT; nrm = xnorm; NR = N_ROWS; }
  else               { r0 = (b - N_ROWS / 8) * 8; src = E; dst = ET; nrm = enorm; NR = N_EMB;  }
  int e = tid & 7, rsub = (tid >> 3) & 7, qg = tid >> 6;   // 8e x 8row x 4qg
  int row = r0 + rsub;
  float s = 0.f;
  #pragma unroll
  for (int qq = 0; qq < 8; qq++){
    int q = qg * 8 + qq;                 // k-chunk [0,32) covering K=256
    float x = src[(size_t)row * C_DIM + q * 8 + e];
    dst[((size_t)q * NR + row) * 8 + e] = (short)f2bf_rne(x);
    s += x * x;
  }
  __shared__ float red[8][33];
  red[rsub][qg * 8 + e] = s;
  __syncthreads();
  if (tid < 8){
    float t = 0.f;
    #pragma unroll
    for (int i = 0; i < 32; i++) t += red[tid][i];
    nrm[r0 + tid] = t;
  }
}

// ---------------- GEMM + fused per-block top3 (no shuffles): BM=256 BN=256 BK=32, 8 waves ----------------
__device__ __forceinline__ void gload16(void* lds, const void* g){
  __builtin_amdgcn_global_load_lds(
      (const __attribute__((address_space(1))) void*)g,
      (__attribute__((address_space(3))) void*)lds, 16, 0, 0);
}

#define VSTR 260   // padded row stride (floats) for the epilogue transpose buffer

__global__ __launch_bounds__(512, 2) void k_gemm(
    const short* __restrict__ XT, const short* __restrict__ ET,
    const float* __restrict__ xnorm, const float* __restrict__ enorm,
    float* __restrict__ out, f32x2* __restrict__ partial)
{
  // One contiguous LDS pool: staging [A/B][buf][4q][256row][8] shorts = 64 KB;
  // epilogue reuses it: vals[32][VSTR] f32 (33.3 KB) + cand2 dbuf (24 KB @ +34 KB).
  __shared__ __align__(16) short SM[2][2][4 * 256 * 8];
  int tid = threadIdx.x;
  int lane = tid & 63, w = tid >> 6;
  int wr = w >> 2, wc = w & 3;          // wave grid 2M x 4N; wave-tile 128 x 64
  // R4/R6-measured swizzle: XCD x owns bn in [4x,4x+4); B slice 512 KB -> L2-resident.
  int id = blockIdx.x;                  // 2048 blocks = 64 bm x 32 bn
  int x = id & 7, jj = id >> 3, c = jj >> 5, u = jj & 31;
  int bm = c * 8 + (u >> 2);            // [0,64)
  int bn = x * 4 + (u & 3);             // [0,32)

  f32x4 acc[8][4];
  #pragma unroll
  for (int m = 0; m < 8; m++)
    #pragma unroll
    for (int n = 0; n < 4; n++) acc[m][n] = (f32x4){0.f, 0.f, 0.f, 0.f};

  // staging one K-tile (K=32) = 32 wave-gloads; wave w takes 4
  auto stage = [&](int buf, int kt){
    #pragma unroll
    for (int i = 0; i < 4; i++){
      int p = w * 4 + i;                // wave-uniform
      if (p < 16){
        int q = p >> 2, qr = p & 3;
        gload16(&SM[0][buf][(q * 256 + qr * 64) * 8],
                XT + ((size_t)(kt * 4 + q) * N_ROWS + (size_t)bm * 256 + qr * 64 + lane) * 8);
      } else {
        int pb = p - 16; int q = pb >> 2, qr = pb & 3;
        gload16(&SM[1][buf][(q * 256 + qr * 64) * 8],
                ET + ((size_t)(kt * 4 + q) * N_EMB + (size_t)bn * 256 + qr * 64 + lane) * 8);
      }
    }
  };

  int r15 = lane & 15, lg4 = lane >> 4;

  stage(0, 0); stage(1, 1);             // 8 loads/wave in flight

  #pragma unroll
  for (int t = 0; t < NKT; ++t){
    const int buf = t & 1;
    if (t < NKT - 1) { asm volatile("s_waitcnt vmcnt(4)" ::: "memory"); }
    else             { asm volatile("s_waitcnt vmcnt(0)" ::: "memory"); }
    __builtin_amdgcn_s_barrier();       // barrier 1: tile t fully in LDS

    bf16x8 af[8], bf[4];
    {
      int q = lg4;
      #pragma unroll
      for (int m = 0; m < 8; m++)
        af[m] = *(const bf16x8*)&SM[0][buf][(q * 256 + wr * 128 + m * 16 + r15) * 8];
      #pragma unroll
      for (int n = 0; n < 4; n++)
        bf[n] = *(const bf16x8*)&SM[1][buf][(q * 256 + wc * 64 + n * 16 + r15) * 8];
    }
    __builtin_amdgcn_s_setprio(1);
    #pragma unroll
    for (int m = 0; m < 4; m++)
      #pragma unroll
      for (int n = 0; n < 4; n++)
        acc[m][n] = __builtin_amdgcn_mfma_f32_16x16x32_bf16(af[m], bf[n], acc[m][n], 0, 0, 0);
    __builtin_amdgcn_s_setprio(0);

    asm volatile("s_waitcnt lgkmcnt(0)" ::: "memory");
    __builtin_amdgcn_sched_barrier(0);
    __builtin_amdgcn_s_barrier();       // barrier 2: all waves done reading buf
    if (t < NKT - 2) stage(buf, t + 2);

    __builtin_amdgcn_s_setprio(1);
    #pragma unroll
    for (int m = 4; m < 8; m++)
      #pragma unroll
      for (int n = 0; n < 4; n++)
        acc[m][n] = __builtin_amdgcn_mfma_f32_16x16x32_bf16(af[m], bf[n], acc[m][n], 0, 0, 0);
    __builtin_amdgcn_s_setprio(0);
  }

  // ---- fused epilogue: dist stores + per-m LDS-transpose top3 reduction (zero shuffles) ----
  // C/D map: col = lane&15, row = (lane>>4)*4 + j.
  float* vals  = (float*)&SM[0][0][0];                       // [32][VSTR]
  f32x2* cand2 = (f32x2*)((char*)&SM[0][0][0] + 34816);      // [2][32][16][3]
  int lc = lane & 15;
  int sr = tid >> 4, st16 = tid & 15;                        // stage1 mapping: 32 rows x 16 threads

  #pragma unroll 8
  for (int m = 0; m < 8; m++){
    if (m > 0){
      asm volatile("s_waitcnt lgkmcnt(0)" ::: "memory");     // drain stage1(m-1) cand2 writes
      __builtin_amdgcn_sched_barrier(0);
      __builtin_amdgcn_s_barrier();                          // B1: vals free, cand2[m-1] visible
    }
    int rb = bm * 256 + wr * 128 + m * 16 + lg4 * 4;
    int row32b = wr * 16 + lg4 * 4;
    float xn0 = xnorm[rb], xn1 = xnorm[rb+1], xn2 = xnorm[rb+2], xn3 = xnorm[rb+3];
    #pragma unroll
    for (int n = 0; n < 4; n++){
      int colL = wc * 64 + n * 16 + lc;
      int col = bn * 256 + colL;
      float en = enorm[col];
      float d0 = xn0 + en - 2.0f * acc[m][n][0];
      float d1 = xn1 + en - 2.0f * acc[m][n][1];
      float d2 = xn2 + en - 2.0f * acc[m][n][2];
      float d3 = xn3 + en - 2.0f * acc[m][n][3];
      out[OFF_DIST + (size_t)(rb + 0) * N_EMB + col] = d0;
      out[OFF_DIST + (size_t)(rb + 1) * N_EMB + col] = d1;
      out[OFF_DIST + (size_t)(rb + 2) * N_EMB + col] = d2;
      out[OFF_DIST + (size_t)(rb + 3) * N_EMB + col] = d3;
      vals[(row32b + 0) * VSTR + colL] = d0;
      vals[(row32b + 1) * VSTR + colL] = d1;
      vals[(row32b + 2) * VSTR + colL] = d2;
      vals[(row32b + 3) * VSTR + colL] = d3;
    }
    asm volatile("s_waitcnt lgkmcnt(0)" ::: "memory");       // drain my vals writes
    __builtin_amdgcn_sched_barrier(0);
    __builtin_amdgcn_s_barrier();                            // B2: vals ready
    // stage1(m): 512 threads = 32 rows x 16; each scans 16 strided cols -> sorted triple
    {
      float v0 = __builtin_inff(), v1 = __builtin_inff(), v2 = __builtin_inff();
      int   i0 = 0x7fffffff,       i1 = 0x7fffffff,       i2 = 0x7fffffff;
      #pragma unroll
      for (int k = 0; k < 16; k++){
        int colL = st16 + k * 16;
        float d = vals[sr * VSTR + colL];
        ins3(d, bn * 256 + colL, v0, i0, v1, i1, v2, i2);
      }
      f32x2* c2 = &cand2[(((m & 1) * 32 + sr) * 16 + st16) * 3];
      c2[0] = (f32x2){v0, __int_as_float(i0)};
      c2[1] = (f32x2){v1, __int_as_float(i1)};
      c2[2] = (f32x2){v2, __int_as_float(i2)};
    }
    // stage2(m-1): 32 threads merge 16 triples -> per-row block triple -> global partial
    if (m > 0 && tid < 32){
      int mp = m - 1;
      float v0 = __builtin_inff(), v1 = __builtin_inff(), v2 = __builtin_inff();
      int   i0 = 0x7fffffff,       i1 = 0x7fffffff,       i2 = 0x7fffffff;
      #pragma unroll
      for (int t16 = 0; t16 < 16; t16++){
        f32x2* c2 = &cand2[(((mp & 1) * 32 + tid) * 16 + t16) * 3];
        #pragma unroll
        for (int s = 0; s < 3; s++){
          f32x2 p = c2[s];
          ins3(p[0], __float_as_int(p[1]), v0, i0, v1, i1, v2, i2);
        }
      }
      int row256 = (tid >> 4) * 128 + mp * 16 + (tid & 15);
      size_t base = ((size_t)(bm * 256 + row256) * 32 + bn) * 3;
      partial[base + 0] = (f32x2){v0, __int_as_float(i0)};
      partial[base + 1] = (f32x2){v1, __int_as_float(i1)};
      partial[base + 2] = (f32x2){v2, __int_as_float(i2)};
    }
  }
  // final stage2(7)
  asm volatile("s_waitcnt lgkmcnt(0)" ::: "memory");
  __builtin_amdgcn_sched_barrier(0);
  __builtin_amdgcn_s_barrier();
  if (tid < 32){
    float v0 = __builtin_inff(), v1 = __builtin_inff(), v2 = __builtin_inff();
    int   i0 = 0x7fffffff,       i1 = 0x7fffffff,       i2 = 0x7fffffff;
    #pragma unroll
    for (int t16 = 0; t16 < 16; t16++){
      f32x2* c2 = &cand2[(((7 & 1) * 32 + tid) * 16 + t16) * 3];
      #pragma unroll
      for (int s = 0; s < 3; s++){
        f32x2 p = c2[s];
        ins3(p[0], __float_as_int(p[1]), v0, i0, v1, i1, v2, i2);
      }
    }
    int row256 = (tid >> 4) * 128 + 7 * 16 + (tid & 15);
    size_t base = ((size_t)(bm * 256 + row256) * 32 + bn) * 3;
    partial[base + 0] = (f32x2){v0, __int_as_float(i0)};
    partial[base + 1] = (f32x2){v1, __int_as_float(i1)};
    partial[base + 2] = (f32x2){v2, __int_as_float(i2)};
  }
}

// ---------------- merge partials -> top3 + quantize + loss partials (1 wave per row) ----------------
__global__ __launch_bounds__(256) void k_mq(
    const f32x2* __restrict__ partial, const float* __restrict__ X, const float* __restrict__ E,
    float* out, int* __restrict__ counts, float* __restrict__ partials)
{
  int wid = threadIdx.x >> 6, lane = threadIdx.x & 63;
  int row = blockIdx.x * 4 + wid;
  const f32x2* pr = partial + (size_t)row * 96;   // 32 bn-tiles x 3 sorted triples
  float v0 = __builtin_inff(), v1 = __builtin_inff(), v2 = __builtin_inff();
  int   i0 = 0x7fffffff,       i1 = 0x7fffffff,       i2 = 0x7fffffff;
  { f32x2 p = pr[lane];      ins3(p[0], __float_as_int(p[1]), v0, i0, v1, i1, v2, i2); }
  if (lane < 32){ f32x2 p = pr[64 + lane]; ins3(p[0], __float_as_int(p[1]), v0, i0, v1, i1, v2, i2); }
  #pragma unroll
  for (int off = 1; off < 64; off <<= 1)
    mrg3(off, v0, i0, v1, i1, v2, i2);
  // butterfly all-reduce: every lane now holds the global sorted triple
  if (lane == 0){
    out[OFF_IDX + (size_t)row * 3 + 0] = (float)i0;
    out[OFF_IDX + (size_t)row * 3 + 1] = (float)i1;
    out[OFF_IDX + (size_t)row * 3 + 2] = (float)i2;
    atomicAdd(&counts[i0], 1); atomicAdd(&counts[i1], 1); atomicAdd(&counts[i2], 1);
  }
  // quantize + straight-through + loss partial (literal STE: x + (e - x))
  int c4 = lane * 4;
  f32x4 x4 = *(const f32x4*)&X[(size_t)row * C_DIM + c4];
  int idx[3] = {i0, i1, i2};
  float lsum = 0.f;
  #pragma unroll
  for (int t = 0; t < 3; t++){
    f32x4 e4 = *(const f32x4*)&E[(size_t)idx[t] * C_DIM + c4];
    #pragma unroll
    for (int q = 0; q < 4; q++){
      float diff = e4[q] - x4[q];
      out[OFF_Q + ((size_t)row * 3 + t) * C_DIM + c4 + q] = x4[q] + diff;
      lsum += diff * diff;
    }
  }
  #pragma unroll
  for (int off = 32; off > 0; off >>= 1) lsum += __shfl_down(lsum, off);
  if (lane == 0) partials[row] = lsum;
}

// ---------------- scalars: loss + perplexity ----------------
__global__ __launch_bounds__(256) void k_final(
    const float* __restrict__ partials, const int* __restrict__ counts,
    float* __restrict__ out)
{
  int t = threadIdx.x;
  float ls = 0.f;
  for (int i = t; i < N_ROWS; i += 256) ls += partials[i];
  float es = 0.f;
  for (int i = t; i < N_EMB; i += 256){
    float p = (float)counts[i] * (1.0f / 16384.0f);
    es += p * logf(p + 1e-10f);
  }
  __shared__ float r1[256], r2[256];
  r1[t] = ls; r2[t] = es; __syncthreads();
  for (int s = 128; s > 0; s >>= 1){
    if (t < s){ r1[t] += r1[t + s]; r2[t] += r2[t + s]; }
    __syncthreads();
  }
  if (t == 0){
    out[OFF_LOSS] = 0.25f * r1[0] / 12582912.0f;
    out[OFF_PERP] = expf(-r2[0]);
  }
}

extern "C" void kernel_launch(void* const* d_in, const int* in_sizes, int n_in,
                              void* d_out, int out_size, void* d_ws, size_t ws_size,
                              hipStream_t stream)
{
  const float* X = (const float*)d_in[0];
  const float* E = (const float*)d_in[1];
  float* out = (float*)d_out;
  char* ws = (char*)d_ws;
  // ws layout (bytes), total ~25.4 MB
  short* XT       = (short*)(ws + 0);          // 8388608   (K-chunk-major bf16)
  short* ET       = (short*)(ws + 8388608);    // 4194304   (K-chunk-major bf16)
  float* xnorm    = (float*)(ws + 12582912);   // 65536
  float* enorm    = (float*)(ws + 12648448);   // 32768
  f32x2* partial  = (f32x2*)(ws + 12681216);   // 16384*32*3*8 = 12582912
  int*   counts   = (int*)  (ws + 25264128);   // 32768
  float* partials = (float*)(ws + 25296896);   // 65536

  hipMemsetAsync(counts, 0, N_EMB * sizeof(int), stream);
  k_prep<<<(N_ROWS + N_EMB) / 8, 256, 0, stream>>>(X, E, XT, ET, xnorm, enorm);
  k_gemm<<<2048, 512, 0, stream>>>(XT, ET, xnorm, enorm, out, partial);
  k_mq<<<N_ROWS / 4, 256, 0, stream>>>(partial, X, E, out, counts, partials);
  k_final<<<1, 256, 0, stream>>>(partials, counts, out);
}

// Round 11
// 347.770 us; speedup vs baseline: 5.6927x; 5.6927x over previous
//
#include <hip/hip_runtime.h>
#include <stdint.h>

// Problem constants
#define N_ROWS 16384   // 16*1024 flattened input rows
#define N_EMB  8192    // codebook size
#define C_DIM  256     // embedding dim
#define NKT    8       // pure-bf16 GEMM: K=256, 8 K-tiles of 32 (R9-validated)

// d_out layout (float element offsets), outputs concatenated in return order:
// loss(1), quantized_st(16*1024*3*256), perplexity(1), encoding_indices(16384*3), distances(16384*8192)
#define OFF_LOSS 0ull
#define OFF_Q    1ull
#define OFF_PERP 12582913ull
#define OFF_IDX  12582914ull
#define OFF_DIST 12632066ull

typedef short bf16x8 __attribute__((ext_vector_type(8)));
typedef float f32x4  __attribute__((ext_vector_type(4)));
typedef float f32x2  __attribute__((ext_vector_type(2)));

// ---------------- prep: fp32 -> bf16 (rne), K-chunk-major layout + fp32 row norms ----------------
// Layout: element (row, k) lives at dst[ ((k>>3)*NR + row)*8 + (k&7) ]
// i.e. [k_chunk][row][8 bf16]: GEMM staging is linear/coalesced AND LDS reads conflict-free.
__device__ __forceinline__ unsigned short f2bf_rne(float f){
  unsigned u = __float_as_uint(f);
  unsigned r = 0x7fffu + ((u >> 16) & 1u);
  return (unsigned short)((u + r) >> 16);
}

__global__ __launch_bounds__(256) void k_prep(
    const float* __restrict__ X, const float* __restrict__ E,
    short* __restrict__ XT, short* __restrict__ ET,
    float* __restrict__ xnorm, float* __restrict__ enorm)
{
  int b = blockIdx.x; int tid = threadIdx.x;
  const float* src; short* dst; float* nrm; int r0, NR;
  if (b < N_ROWS / 8){ r0 = b * 8;                src = X; dst = XT; nrm = xnorm; NR = N_ROWS; }
  else               { r0 = (b - N_ROWS / 8) * 8; src = E; dst = ET; nrm = enorm; NR = N_EMB;  }
  int e = tid & 7, rsub = (tid >> 3) & 7, qg = tid >> 6;   // 8e x 8row x 4qg
  int row = r0 + rsub;
  float s = 0.f;
  #pragma unroll
  for (int qq = 0; qq < 8; qq++){
    int q = qg * 8 + qq;                 // k-chunk [0,32) covering K=256
    float x = src[(size_t)row * C_DIM + q * 8 + e];
    dst[((size_t)q * NR + row) * 8 + e] = (short)f2bf_rne(x);
    s += x * x;
  }
  __shared__ float red[8][33];
  red[rsub][qg * 8 + e] = s;
  __syncthreads();
  if (tid < 8){
    float t = 0.f;
    #pragma unroll
    for (int i = 0; i < 32; i++) t += red[tid][i];
    nrm[r0 + tid] = t;
  }
}

// ---------------- GEMM: BM=256 BN=256 BK=32, 8 waves (2M x 4N of 128x64 wave-tiles) ----------------
// R9-exact. LDS 64 KB (dbuf 2 x 32 KB); launch_bounds(512,2): VGPR=128 no spill -> 2 blocks/CU.
// Counted-vmcnt pipeline, raw barriers, plain-store epilogue. Fused top-k REJECTED (R4: shfl storm,
// R10: I-cache/barrier pathology, 13x regression) — keep this epilogue dumb and compact.
__device__ __forceinline__ void gload16(void* lds, const void* g){
  __builtin_amdgcn_global_load_lds(
      (const __attribute__((address_space(1))) void*)g,
      (__attribute__((address_space(3))) void*)lds, 16, 0, 0);
}

__global__ __launch_bounds__(512, 2) void k_gemm(
    const short* __restrict__ XT, const short* __restrict__ ET,
    const float* __restrict__ xnorm, const float* __restrict__ enorm,
    float* __restrict__ out)
{
  // LDS: [buf][q=0..3][row 0..255][8 bf16]; 16 KB per matrix per buffer = 64 KB total
  __shared__ __align__(16) short As[2][4 * 256 * 8];
  __shared__ __align__(16) short Bs[2][4 * 256 * 8];
  int tid = threadIdx.x;
  int lane = tid & 63, w = tid >> 6;
  int wr = w >> 2, wc = w & 3;          // wave grid 2M x 4N; wave-tile 128 x 64
  // R4/R6-measured swizzle: XCD x owns bn in [4x,4x+4); B slice 512 KB -> L2-resident.
  int id = blockIdx.x;                  // 2048 blocks = 64 bm x 32 bn
  int x = id & 7, jj = id >> 3, c = jj >> 5, u = jj & 31;
  int bm = c * 8 + (u >> 2);            // [0,64)
  int bn = x * 4 + (u & 3);             // [0,32)

  f32x4 acc[8][4];
  #pragma unroll
  for (int m = 0; m < 8; m++)
    #pragma unroll
    for (int n = 0; n < 4; n++) acc[m][n] = (f32x4){0.f, 0.f, 0.f, 0.f};

  // staging one K-tile (K=32) = 32 wave-gloads (A: 4q x 4 quarters, B: same); wave w takes 4
  auto stage = [&](int buf, int kt){
    #pragma unroll
    for (int i = 0; i < 4; i++){
      int p = w * 4 + i;                // wave-uniform
      if (p < 16){
        int q = p >> 2, qr = p & 3;
        gload16(&As[buf][(q * 256 + qr * 64) * 8],
                XT + ((size_t)(kt * 4 + q) * N_ROWS + (size_t)bm * 256 + qr * 64 + lane) * 8);
      } else {
        int pb = p - 16; int q = pb >> 2, qr = pb & 3;
        gload16(&Bs[buf][(q * 256 + qr * 64) * 8],
                ET + ((size_t)(kt * 4 + q) * N_EMB + (size_t)bn * 256 + qr * 64 + lane) * 8);
      }
    }
  };

  int r15 = lane & 15, lg4 = lane >> 4;

  stage(0, 0); stage(1, 1);             // 8 loads/wave in flight

  #pragma unroll
  for (int t = 0; t < NKT; ++t){
    const int buf = t & 1;
    // tile t ready: only tile t+1's 4 loads may remain in flight.
    if (t < NKT - 1) { asm volatile("s_waitcnt vmcnt(4)" ::: "memory"); }
    else             { asm volatile("s_waitcnt vmcnt(0)" ::: "memory"); }
    __builtin_amdgcn_s_barrier();       // barrier 1: tile t fully in LDS

    bf16x8 af[8], bf[4];
    {
      int q = lg4;                      // q in [0,4): K = q*8 .. q*8+7 within this 32-K tile
      #pragma unroll
      for (int m = 0; m < 8; m++)
        af[m] = *(const bf16x8*)&As[buf][(q * 256 + wr * 128 + m * 16 + r15) * 8];
      #pragma unroll
      for (int n = 0; n < 4; n++)
        bf[n] = *(const bf16x8*)&Bs[buf][(q * 256 + wc * 64 + n * 16 + r15) * 8];
    }
    // MFMA cluster 0 (m 0..3)
    __builtin_amdgcn_s_setprio(1);
    #pragma unroll
    for (int m = 0; m < 4; m++)
      #pragma unroll
      for (int n = 0; n < 4; n++)
        acc[m][n] = __builtin_amdgcn_mfma_f32_16x16x32_bf16(af[m], bf[n], acc[m][n], 0, 0, 0);
    __builtin_amdgcn_s_setprio(0);

    asm volatile("s_waitcnt lgkmcnt(0)" ::: "memory"); // all my ds_reads of buf done
    __builtin_amdgcn_sched_barrier(0);
    __builtin_amdgcn_s_barrier();       // barrier 2: all waves done reading buf
    if (t < NKT - 2) stage(buf, t + 2); // restage into dead buffer

    // MFMA cluster 1 (m 4..7) — hides the stage issue
    __builtin_amdgcn_s_setprio(1);
    #pragma unroll
    for (int m = 4; m < 8; m++)
      #pragma unroll
      for (int n = 0; n < 4; n++)
        acc[m][n] = __builtin_amdgcn_mfma_f32_16x16x32_bf16(af[m], bf[n], acc[m][n], 0, 0, 0);
    __builtin_amdgcn_s_setprio(0);
  }

  // epilogue: dist = ||x||^2 + ||e||^2 - 2*dot  (C/D map: col=lane&15, row=(lane>>4)*4+j)
  // Plain per-lane stores; adjacent n-iterations complete each 128 B line in L2 (clean 537 MB).
  int lc = lane & 15;
  #pragma unroll
  for (int m = 0; m < 8; m++){
    int rb = bm * 256 + wr * 128 + m * 16 + lg4 * 4;
    float xn0 = xnorm[rb], xn1 = xnorm[rb+1], xn2 = xnorm[rb+2], xn3 = xnorm[rb+3];
    #pragma unroll
    for (int n = 0; n < 4; n++){
      int col = bn * 256 + wc * 64 + n * 16 + lc;
      float en = enorm[col];
      out[OFF_DIST + (size_t)(rb + 0) * N_EMB + col] = xn0 + en - 2.0f * acc[m][n][0];
      out[OFF_DIST + (size_t)(rb + 1) * N_EMB + col] = xn1 + en - 2.0f * acc[m][n][1];
      out[OFF_DIST + (size_t)(rb + 2) * N_EMB + col] = xn2 + en - 2.0f * acc[m][n][2];
      out[OFF_DIST + (size_t)(rb + 3) * N_EMB + col] = xn3 + en - 2.0f * acc[m][n][3];
    }
  }
}

// ---------------- top-3 per row + quantize + loss partial (fused; tie-break = jax.lax.top_k) ----------------
#define LT(av,ai,bv,bi) (((av) < (bv)) || ((av) == (bv) && (ai) < (bi)))

__global__ __launch_bounds__(256) void k_tq(
    const float* __restrict__ X, const float* __restrict__ E,
    float* out, int* __restrict__ counts, float* __restrict__ partials)
{
  int row = blockIdx.x; int tid = threadIdx.x;
  const f32x4* drow = (const f32x4*)(out + OFF_DIST + (size_t)row * N_EMB);
  float v0 = __builtin_inff(), v1 = __builtin_inff(), v2 = __builtin_inff();
  int   i0 = 0x7fffffff,       i1 = 0x7fffffff,       i2 = 0x7fffffff;
  for (int i = tid; i < N_EMB / 4; i += 256){
    f32x4 dv = __builtin_nontemporal_load(&drow[i]);
    #pragma unroll
    for (int j = 0; j < 4; j++){
      float d = dv[j]; int ii = i * 4 + j;
      if (LT(d, ii, v2, i2)){
        if (LT(d, ii, v1, i1)){
          v2 = v1; i2 = i1;
          if (LT(d, ii, v0, i0)){ v1 = v0; i1 = i0; v0 = d; i0 = ii; }
          else                  { v1 = d;  i1 = ii; }
        } else { v2 = d; i2 = ii; }
      }
    }
  }
  // wave butterfly merge of sorted triples
  #pragma unroll
  for (int off = 1; off < 64; off <<= 1){
    float b0 = __shfl_xor(v0, off), b1 = __shfl_xor(v1, off), b2 = __shfl_xor(v2, off);
    int   j0 = __shfl_xor(i0, off), j1 = __shfl_xor(i1, off), j2 = __shfl_xor(i2, off);
    float a0 = v0, a1 = v1, a2 = v2; int x0 = i0, x1 = i1, x2 = i2;
    float r0, r1, r2; int s0, s1, s2;
    if (LT(a0, x0, b0, j0)){ r0 = a0; s0 = x0; a0 = a1; x0 = x1; a1 = a2; x1 = x2; a2 = __builtin_inff(); x2 = 0x7fffffff; }
    else                   { r0 = b0; s0 = j0; b0 = b1; j0 = j1; b1 = b2; j1 = j2; b2 = __builtin_inff(); j2 = 0x7fffffff; }
    if (LT(a0, x0, b0, j0)){ r1 = a0; s1 = x0; a0 = a1; x0 = x1; a1 = a2; x1 = x2; a2 = __builtin_inff(); x2 = 0x7fffffff; }
    else                   { r1 = b0; s1 = j0; b0 = b1; j0 = j1; b1 = b2; j1 = j2; b2 = __builtin_inff(); j2 = 0x7fffffff; }
    if (LT(a0, x0, b0, j0)){ r2 = a0; s2 = x0; }
    else                   { r2 = b0; s2 = j0; }
    v0 = r0; i0 = s0; v1 = r1; i1 = s1; v2 = r2; i2 = s2;
  }
  __shared__ float swv[4][3]; __shared__ int swi[4][3];
  int lane = tid & 63, wid = tid >> 6;
  if (lane == 0){
    swv[wid][0] = v0; swv[wid][1] = v1; swv[wid][2] = v2;
    swi[wid][0] = i0; swi[wid][1] = i1; swi[wid][2] = i2;
  }
  __syncthreads();
  if (tid == 0){
    for (int wq = 1; wq < 4; wq++){
      for (int t = 0; t < 3; t++){
        float d = swv[wq][t]; int i = swi[wq][t];
        if (LT(d, i, v2, i2)){
          if (LT(d, i, v1, i1)){
            v2 = v1; i2 = i1;
            if (LT(d, i, v0, i0)){ v1 = v0; i1 = i0; v0 = d; i0 = i; }
            else                 { v1 = d;  i1 = i; }
          } else { v2 = d; i2 = i; }
        }
      }
    }
    out[OFF_IDX + (size_t)row * 3 + 0] = (float)i0;
    out[OFF_IDX + (size_t)row * 3 + 1] = (float)i1;
    out[OFF_IDX + (size_t)row * 3 + 2] = (float)i2;
    swi[0][0] = i0; swi[0][1] = i1; swi[0][2] = i2;   // broadcast final triple
    atomicAdd(&counts[i0], 1); atomicAdd(&counts[i1], 1); atomicAdd(&counts[i2], 1);
  }
  __syncthreads();
  // quantize + straight-through + loss partial (literal STE: x + (e - x)); c = tid
  int fi0 = swi[0][0], fi1 = swi[0][1], fi2 = swi[0][2];
  float xv = X[(size_t)row * C_DIM + tid];
  float lsum = 0.f;
  {
    float e = E[(size_t)fi0 * C_DIM + tid]; float d = e - xv;
    out[OFF_Q + ((size_t)row * 3 + 0) * C_DIM + tid] = xv + d; lsum += d * d;
  }
  {
    float e = E[(size_t)fi1 * C_DIM + tid]; float d = e - xv;
    out[OFF_Q + ((size_t)row * 3 + 1) * C_DIM + tid] = xv + d; lsum += d * d;
  }
  {
    float e = E[(size_t)fi2 * C_DIM + tid]; float d = e - xv;
    out[OFF_Q + ((size_t)row * 3 + 2) * C_DIM + tid] = xv + d; lsum += d * d;
  }
  __shared__ float qred[256];
  qred[tid] = lsum; __syncthreads();
  for (int s = 128; s > 0; s >>= 1){ if (tid < s) qred[tid] += qred[tid + s]; __syncthreads(); }
  if (tid == 0) partials[row] = qred[0];
}

// ---------------- scalars: loss + perplexity ----------------
__global__ __launch_bounds__(256) void k_final(
    const float* __restrict__ partials, const int* __restrict__ counts,
    float* __restrict__ out)
{
  int t = threadIdx.x;
  float ls = 0.f;
  for (int i = t; i < N_ROWS; i += 256) ls += partials[i];
  float es = 0.f;
  for (int i = t; i < N_EMB; i += 256){
    float p = (float)counts[i] * (1.0f / 16384.0f);
    es += p * logf(p + 1e-10f);
  }
  __shared__ float r1[256], r2[256];
  r1[t] = ls; r2[t] = es; __syncthreads();
  for (int s = 128; s > 0; s >>= 1){
    if (t < s){ r1[t] += r1[t + s]; r2[t] += r2[t + s]; }
    __syncthreads();
  }
  if (t == 0){
    out[OFF_LOSS] = 0.25f * r1[0] / 12582912.0f;
    out[OFF_PERP] = expf(-r2[0]);
  }
}

extern "C" void kernel_launch(void* const* d_in, const int* in_sizes, int n_in,
                              void* d_out, int out_size, void* d_ws, size_t ws_size,
                              hipStream_t stream)
{
  const float* X = (const float*)d_in[0];
  const float* E = (const float*)d_in[1];
  float* out = (float*)d_out;
  char* ws = (char*)d_ws;
  // ws layout (bytes), total ~12.8 MB
  short* XT       = (short*)(ws + 0);          // 8388608   (K-chunk-major bf16)
  short* ET       = (short*)(ws + 8388608);    // 4194304   (K-chunk-major bf16)
  float* xnorm    = (float*)(ws + 12582912);   // 65536
  float* enorm    = (float*)(ws + 12648448);   // 32768
  int*   counts   = (int*)  (ws + 12681216);   // 32768
  float* partials = (float*)(ws + 12713984);   // 65536

  hipMemsetAsync(counts, 0, N_EMB * sizeof(int), stream);
  k_prep<<<(N_ROWS + N_EMB) / 8, 256, 0, stream>>>(X, E, XT, ET, xnorm, enorm);
  k_gemm<<<2048, 512, 0, stream>>>(XT, ET, xnorm, enorm, out);
  k_tq<<<N_ROWS, 256, 0, stream>>>(X, E, out, counts, partials);
  k_final<<<1, 256, 0, stream>>>(partials, counts, out);
}